// Round 1
// baseline (737.687 us; speedup 1.0000x reference)
//
#include <hip/hip_runtime.h>
#include <stdint.h>

#define NTOK  4096
#define BATCH 32
#define CH    768
#define KKEEP 2458          // ceil(4096 * 0.6)
#define TPB   256
#define EPT   (NTOK / TPB)  // 16 elements per thread

// ---------------------------------------------------------------------------
// Kernel 1: one block per batch row. Computes the combined normalized score
// bitwise-identically to the JAX reference, then finds the exact k-th largest
// via 32-pass radix select on the (non-negative) float bit patterns, and
// writes the 0/1 mask with jax.lax.top_k's stable tie-breaking (lower index
// wins among equal scores).
// ---------------------------------------------------------------------------
__global__ __launch_bounds__(TPB) void score_mask_kernel(
    const float* __restrict__ s1g,
    const float* __restrict__ s2g,
    const float* __restrict__ s3g,
    float* __restrict__ mask_out)
{
    const int b    = blockIdx.x;
    const int tid  = threadIdx.x;
    const int lane = tid & 63;
    const int wave = tid >> 6;

    const float* s1 = s1g + b * NTOK;
    const float* s2 = s2g + b * NTOK;
    const float* s3 = s3g + b * NTOK;

    __shared__ uint32_t sscore[NTOK];   // 16 KB: score bit patterns
    __shared__ float    rmn[3][4], rmx[3][4];
    __shared__ uint32_t cntArr[34];     // slots 0..31: radix passes, 32: G

    if (tid < 34) cntArr[tid] = 0;

    // ---- load rows, per-thread min/max ----
    float v1[EPT], v2[EPT], v3[EPT];
    float mn1 = 3.4e38f, mx1 = -3.4e38f;
    float mn2 = 3.4e38f, mx2 = -3.4e38f;
    float mn3 = 3.4e38f, mx3 = -3.4e38f;
#pragma unroll
    for (int e = 0; e < EPT; ++e) {
        const int i = tid + e * TPB;
        v1[e] = s1[i]; v2[e] = s2[i]; v3[e] = s3[i];
        mn1 = fminf(mn1, v1[e]); mx1 = fmaxf(mx1, v1[e]);
        mn2 = fminf(mn2, v2[e]); mx2 = fmaxf(mx2, v2[e]);
        mn3 = fminf(mn3, v3[e]); mx3 = fmaxf(mx3, v3[e]);
    }
    // ---- wave reduce (64 lanes) ----
#pragma unroll
    for (int off = 32; off > 0; off >>= 1) {
        mn1 = fminf(mn1, __shfl_xor(mn1, off, 64));
        mx1 = fmaxf(mx1, __shfl_xor(mx1, off, 64));
        mn2 = fminf(mn2, __shfl_xor(mn2, off, 64));
        mx2 = fmaxf(mx2, __shfl_xor(mx2, off, 64));
        mn3 = fminf(mn3, __shfl_xor(mn3, off, 64));
        mx3 = fmaxf(mx3, __shfl_xor(mx3, off, 64));
    }
    if (lane == 0) {
        rmn[0][wave] = mn1; rmx[0][wave] = mx1;
        rmn[1][wave] = mn2; rmx[1][wave] = mx2;
        rmn[2][wave] = mn3; rmx[2][wave] = mx3;
    }
    __syncthreads();
    // cross-wave combine (redundant per-thread, broadcast reads — cheap)
    mn1 = fminf(fminf(rmn[0][0], rmn[0][1]), fminf(rmn[0][2], rmn[0][3]));
    mx1 = fmaxf(fmaxf(rmx[0][0], rmx[0][1]), fmaxf(rmx[0][2], rmx[0][3]));
    mn2 = fminf(fminf(rmn[1][0], rmn[1][1]), fminf(rmn[1][2], rmn[1][3]));
    mx2 = fmaxf(fmaxf(rmx[1][0], rmx[1][1]), fmaxf(rmx[1][2], rmx[1][3]));
    mn3 = fminf(fminf(rmn[2][0], rmn[2][1]), fminf(rmn[2][2], rmn[2][3]));
    mx3 = fmaxf(fmaxf(rmx[2][0], rmx[2][1]), fmaxf(rmx[2][2], rmx[2][3]));

    // denominators exactly as JAX: (max - min) + 1e-8  (fp32, IEEE)
    const float d1 = (mx1 - mn1) + 1e-8f;
    const float d2 = (mx2 - mn2) + 1e-8f;
    const float d3 = (mx3 - mn3) + 1e-8f;

    // ---- combined score, bitwise identical to reference ----
    uint32_t sbits[EPT];
#pragma unroll
    for (int e = 0; e < EPT; ++e) {
        const int i = tid + e * TPB;
        const float n1 = (v1[e] - mn1) / d1;
        const float n2 = (v2[e] - mn2) / d2;
        const float n3 = (v3[e] - mn3) / d3;
        const float sc = ((n1 + n2) + n3) / 3.0f;   // all scores >= 0
        const uint32_t x = __float_as_uint(sc);
        sbits[e]  = x;
        sscore[i] = x;
    }
    __syncthreads();

    // ---- radix select: largest prefix with count(x >= prefix) >= K ----
    uint32_t prefix = 0;
    for (int bit = 31; bit >= 0; --bit) {
        const uint32_t cand = prefix | (1u << bit);
        int local = 0;
#pragma unroll
        for (int e = 0; e < EPT; ++e) local += (sbits[e] >= cand) ? 1 : 0;
#pragma unroll
        for (int off = 32; off > 0; off >>= 1) local += __shfl_xor(local, off, 64);
        if (lane == 0) atomicAdd(&cntArr[bit], (uint32_t)local);
        __syncthreads();
        if (cntArr[bit] >= KKEEP) prefix = cand;
        // no extra barrier: next pass atomics hit a different slot
    }
    // prefix == exact k-th largest score bits (t)

    // ---- G = count(x > t) ----
    {
        int local = 0;
#pragma unroll
        for (int e = 0; e < EPT; ++e) local += (sbits[e] > prefix) ? 1 : 0;
#pragma unroll
        for (int off = 32; off > 0; off >>= 1) local += __shfl_xor(local, off, 64);
        if (lane == 0) atomicAdd(&cntArr[32], (uint32_t)local);
        __syncthreads();
    }
    const int G = (int)cntArr[32];

    // ---- write mask with stable tie-breaking ----
#pragma unroll
    for (int e = 0; e < EPT; ++e) {
        const int i = tid + e * TPB;
        const uint32_t x = sbits[e];
        float m;
        if (x > prefix) {
            m = 1.0f;
        } else if (x < prefix) {
            m = 0.0f;
        } else {
            // equal to threshold: keep lowest indices first (top_k is stable)
            int before = 0;
            for (int j = 0; j < i; ++j) before += (sscore[j] == prefix) ? 1 : 0;
            m = (G + before < KKEEP) ? 1.0f : 0.0f;
        }
        mask_out[b * NTOK + i] = m;
    }
}

// ---------------------------------------------------------------------------
// Kernel 2: out[b,n,:] = tokens[b,n,:] * mask[b,n]. float4-vectorized,
// grid-stride. C = 768 floats = 192 float4 = 3 full waves -> mask is
// wave-uniform, so masked-out waves skip the token read entirely
// (saves 40% of read traffic with zero divergence).
// ---------------------------------------------------------------------------
__global__ __launch_bounds__(256) void mask_mul_kernel(
    const float4* __restrict__ tok,
    const float*  __restrict__ mask,
    float4* __restrict__ out,
    int total4)
{
    const int stride = gridDim.x * blockDim.x;
    for (int i = blockIdx.x * blockDim.x + threadIdx.x; i < total4; i += stride) {
        const int token = i / (CH / 4);   // /192, magic-mul
        const float m = mask[token];      // wave-uniform broadcast
        float4 v;
        if (m != 0.0f) {
            v = tok[i];                   // kept: tokens * 1.0 == tokens
        } else {
            v = make_float4(0.f, 0.f, 0.f, 0.f);
        }
        out[i] = v;
    }
}

extern "C" void kernel_launch(void* const* d_in, const int* in_sizes, int n_in,
                              void* d_out, int out_size, void* d_ws, size_t ws_size,
                              hipStream_t stream) {
    const float* tokens = (const float*)d_in[0];
    const float* sa     = (const float*)d_in[1];
    const float* c2     = (const float*)d_in[2];
    const float* c3     = (const float*)d_in[3];

    float* out      = (float*)d_out;
    float* mask_out = out + (size_t)BATCH * NTOK * CH;   // mask region of d_out

    score_mask_kernel<<<BATCH, TPB, 0, stream>>>(sa, c2, c3, mask_out);

    const int total4 = BATCH * NTOK * (CH / 4);          // 25,165,824 float4
    mask_mul_kernel<<<2048, 256, 0, stream>>>(
        (const float4*)tokens, mask_out, (float4*)out, total4);
}